// Round 13
// baseline (368.623 us; speedup 1.0000x reference)
//
#include <hip/hip_runtime.h>

typedef unsigned short u16;
typedef unsigned int u32;
typedef __attribute__((ext_vector_type(8))) short s16x8;
typedef __attribute__((ext_vector_type(4))) float f32x4;

__device__ __forceinline__ float bf2f(u32 u) {
    return __uint_as_float(u << 16);
}
__device__ __forceinline__ u16 f2bf(float f) {
    u32 x = __float_as_uint(f);
    u32 r = (x + 0x7fffu + ((x >> 16) & 1u)) >> 16;   // round-nearest-even
    return (u16)r;
}

__device__ __forceinline__ void gload16(const u16* g, u16* l) {
    __builtin_amdgcn_global_load_lds(
        (const __attribute__((address_space(1))) unsigned int*)g,
        (__attribute__((address_space(3))) unsigned int*)l,
        16, 0, 0);
}

// leaky-relu then clamp: overflow-safe shiftless softmax (exact; logits O(10))
__device__ __forceinline__ float lk60(float e) {
    e = (e > 0.f) ? e : 0.2f * e;
    return fminf(e, 60.f);
}

// ---------------------------------------------------------------- fused prep + edge count
__global__ __launch_bounds__(256) void prep_k(
    const int* __restrict__ edst,  int* __restrict__ cnt, int E_,
    const float* __restrict__ x, const float* __restrict__ W1,
    const float* __restrict__ W2, const float* __restrict__ W3,
    u16* __restrict__ xb, u16* __restrict__ Wt1,
    u16* __restrict__ Wt2, u16* __restrict__ Wt3, int N, int Mp, int ETB)
{
    if ((int)blockIdx.x < ETB) {
        const int i = blockIdx.x * 256 + threadIdx.x;
        if (i >= E_ + N) return;
        const int d = (i < E_) ? edst[i] : (i - E_);
        atomicAdd(&cnt[d], 1);
        return;
    }
    const int i = ((int)blockIdx.x - ETB) * 256 + threadIdx.x;
    const int n1 = Mp * 96;
    const int n2 = 512 * 96;
    const int n3 = 512 * 512;
    const int n4 = 128 * 512;
    if (i < n1) {
        const int r = i / 96, c = i - r * 96;
        xb[i] = f2bf((r < N && c < 75) ? x[(size_t)r * 75 + c] : 0.f);
    } else if (i < n1 + n2) {
        const int j = i - n1;
        const int n = j / 96, k = j - n * 96;
        Wt1[j] = f2bf(k < 75 ? W1[(size_t)k * 512 + n] : 0.f);
    } else if (i < n1 + n2 + n3) {
        const int j = i - n1 - n2;
        const int n = j >> 9, k = j & 511;
        Wt2[j] = f2bf(W2[(size_t)k * 512 + n]);
    } else if (i < n1 + n2 + n3 + n4) {
        const int j = i - n1 - n2 - n3;
        const int n = j >> 9, k = j & 511;
        Wt3[j] = f2bf(W3[(size_t)k * 128 + n]);
    }
}

// ---------------------------------------------------------------- 3-kernel scan
#define SCAN_B 256
__global__ void scan1_k(const int* __restrict__ cnt, int* __restrict__ part,
                        int* __restrict__ bsum, int n)
{
    __shared__ int sm[SCAN_B];
    const int idx = blockIdx.x * SCAN_B + threadIdx.x;
    int v = (idx < n) ? cnt[idx] : 0;
    sm[threadIdx.x] = v;
    __syncthreads();
    for (int off = 1; off < SCAN_B; off <<= 1) {
        int t2 = (threadIdx.x >= off) ? sm[threadIdx.x - off] : 0;
        __syncthreads();
        sm[threadIdx.x] += t2;
        __syncthreads();
    }
    if (idx < n) part[idx] = sm[threadIdx.x];
    if (threadIdx.x == SCAN_B - 1) bsum[blockIdx.x] = sm[threadIdx.x];
}

__global__ void scan2_k(int* __restrict__ bsum, int nb)
{
    __shared__ int sm[SCAN_B];
    const int t = threadIdx.x;
    int v = (t < nb) ? bsum[t] : 0;
    sm[t] = v;
    __syncthreads();
    for (int off = 1; off < SCAN_B; off <<= 1) {
        int t2 = (t >= off) ? sm[t - off] : 0;
        __syncthreads();
        sm[t] += t2;
        __syncthreads();
    }
    if (t < nb) bsum[t] = sm[t] - v;   // exclusive
}

__global__ void scan3_k(const int* __restrict__ part, const int* __restrict__ boff,
                        int* __restrict__ offs, int n)
{
    const int idx = blockIdx.x * SCAN_B + threadIdx.x;
    if (idx < n) offs[idx + 1] = part[idx] + boff[idx / SCAN_B];
    if (idx == 0) offs[0] = 0;
}

// ---------------------------------------------------------------- MFMA GEMM + fused logits
__global__ __launch_bounds__(256) void mgemm_k(
    const u16* __restrict__ A, const u16* __restrict__ Bt, u16* __restrict__ C,
    const float* __restrict__ avs, const float* __restrict__ avd,
    float* __restrict__ als, float* __restrict__ ald,
    int M, int K, int Ncol, int H, int NXB)
{
    __shared__ u16 Al[2][128 * 32];
    __shared__ u16 Bl[2][128 * 32];
    const int t = threadIdx.x;
    const int lane = t & 63;
    const int wid = t >> 6;
    const int wr = wid >> 1, wc = wid & 1;
    const int rr = lane & 15, q = lane >> 4;

    const int dd = blockIdx.x;
    const int xcd = dd & 7, ii = dd >> 3;
    const int gpx = (int)(gridDim.x >> 3) / NXB;
    const int yb = xcd * gpx + ((NXB == 4) ? (ii >> 2) : ii);
    const int head = (NXB == 4) ? (ii & 3) : 0;
    const int m0 = yb * 128, n0 = head * 128;

    f32x4 acc[4][4];
#pragma unroll
    for (int m = 0; m < 4; ++m)
#pragma unroll
        for (int n = 0; n < 4; ++n) acc[m][n] = (f32x4){0.f, 0.f, 0.f, 0.f};

    auto stage = [&](int b, int k0) {
#pragma unroll
        for (int i2 = 0; i2 < 2; ++i2) {
            const int si = i2 * 256 + t;
            const int r = si >> 2, s = si & 3;
            const int g = s ^ ((r >> 1) & 3);
            gload16(A  + (size_t)(m0 + r) * K + k0 + g * 8, &Al[b][si * 8]);
            gload16(Bt + (size_t)(n0 + r) * K + k0 + g * 8, &Bl[b][si * 8]);
        }
    };

    const int nk = K >> 5;
    stage(0, 0);
    __syncthreads();
    int buf = 0;
    for (int kt = 0; kt < nk; ++kt) {
        if (kt + 1 < nk) stage(buf ^ 1, (kt + 1) << 5);
        s16x8 af[4], bfr[4];
#pragma unroll
        for (int m = 0; m < 4; ++m) {
            const int r = wr * 64 + m * 16 + rr;
            af[m] = *reinterpret_cast<const s16x8*>(&Al[buf][r * 32 + ((q ^ ((r >> 1) & 3)) << 3)]);
        }
#pragma unroll
        for (int n = 0; n < 4; ++n) {
            const int r = wc * 64 + n * 16 + rr;
            bfr[n] = *reinterpret_cast<const s16x8*>(&Bl[buf][r * 32 + ((q ^ ((r >> 1) & 3)) << 3)]);
        }
#pragma unroll
        for (int m = 0; m < 4; ++m)
#pragma unroll
            for (int n = 0; n < 4; ++n)
                acc[m][n] = __builtin_amdgcn_mfma_f32_16x16x32_bf16(af[m], bfr[n], acc[m][n], 0, 0, 0);
        __syncthreads();
        buf ^= 1;
    }

#pragma unroll
    for (int m = 0; m < 4; ++m) {
        const int row_b = m0 + wr * 64 + m * 16 + q * 4;
#pragma unroll
        for (int j = 0; j < 4; ++j) {
            const int row = row_b + j;
            if (row < M) {
#pragma unroll
                for (int n = 0; n < 4; ++n) {
                    const int col = n0 + wc * 64 + n * 16 + rr;
                    C[(size_t)row * Ncol + col] = f2bf(acc[m][n][j]);
                }
            }
        }
    }

    // fused logits
    float asv[4], adv[4];
#pragma unroll
    for (int n = 0; n < 4; ++n) {
        const int c = wc * 64 + n * 16 + rr;
        asv[n] = avs[head * 128 + c];
        adv[n] = avd[head * 128 + c];
    }
    float* lps = (float*)&Al[0][0];
    float* lpd = lps + 256;
#pragma unroll
    for (int m = 0; m < 4; ++m)
#pragma unroll
        for (int j = 0; j < 4; ++j) {
            float ps = 0.f, pd = 0.f;
#pragma unroll
            for (int n = 0; n < 4; ++n) {
                ps += acc[m][n][j] * asv[n];
                pd += acc[m][n][j] * adv[n];
            }
#pragma unroll
            for (int off = 1; off < 16; off <<= 1) {
                ps += __shfl_xor(ps, off, 64);
                pd += __shfl_xor(pd, off, 64);
            }
            if (rr == 0) {
                const int r = wr * 64 + m * 16 + q * 4 + j;
                lps[wc * 128 + r] = ps;
                lpd[wc * 128 + r] = pd;
            }
        }
    __syncthreads();
    if (t < 128) {
        const int row = m0 + t;
        if (row < M) {
            als[(size_t)row * H + head] = lps[t] + lps[128 + t];
            ald[(size_t)row * H + head] = lpd[t] + lpd[128 + t];
        }
    }
}

// ---------------------------------------------------------------- scatter
__global__ void scatter_k(const int* __restrict__ esrc, const int* __restrict__ edst,
                          const int* __restrict__ offs, int* __restrict__ fill,
                          int* __restrict__ csr, int E_, int N_)
{
    const int i = blockIdx.x * 256 + threadIdx.x;
    if (i >= E_ + N_) return;
    int s, d;
    if (i < E_) { s = esrc[i]; d = edst[i]; } else { s = d = i - E_; }
    const int pos = offs[d] + atomicAdd(&fill[d], 1);
    csr[pos] = s;
}

// ---------------------------------------------------------------- aggregate CH=512 (+BN+ReLU)
// one wave per dst; ONE-sweep unnormalized softmax (per-lane smw, divide at
// end); gather 4 edges in flight, 16B/lane. Proven fastest (r10: 72.9 us).
template<bool RELU>
__global__ __launch_bounds__(256) void agg512_k(
    const u16* __restrict__ hsrc, const int* __restrict__ offs,
    const int* __restrict__ csr, const float* __restrict__ als,
    const float* __restrict__ ald, const float* __restrict__ bias,
    const float* __restrict__ gam, const float* __restrict__ bet,
    const float* __restrict__ rmean, const float* __restrict__ rvar,
    u16* __restrict__ outp, int N)
{
    const int lane = threadIdx.x & 63;
    const int dst = blockIdx.x * 4 + (threadIdx.x >> 6);
    if (dst >= N) return;
    const int ch0 = lane * 8;
    const int hd = lane >> 4;

    const float advh = ald[(size_t)dst * 4 + hd];
    const int rs = offs[dst], re = offs[dst + 1];

    float acc[8] = {};
    float smw = 0.f;
    int s = rs;
    for (; s + 4 <= re; s += 4) {
        int sn[4];
#pragma unroll
        for (int u = 0; u < 4; ++u) sn[u] = csr[s + u];
        int4 r[4];
#pragma unroll
        for (int u = 0; u < 4; ++u)
            r[u] = *reinterpret_cast<const int4*>(hsrc + (size_t)sn[u] * 512 + ch0);
        float aa[4];
#pragma unroll
        for (int u = 0; u < 4; ++u)
            aa[u] = __expf(lk60(als[(size_t)sn[u] * 4 + hd] + advh));
#pragma unroll
        for (int u = 0; u < 4; ++u) {
            smw += aa[u];
            const u32 rr2[4] = {(u32)r[u].x, (u32)r[u].y, (u32)r[u].z, (u32)r[u].w};
#pragma unroll
            for (int qq = 0; qq < 4; ++qq) {
                acc[2*qq]   += aa[u] * bf2f(rr2[qq] & 0xffffu);
                acc[2*qq+1] += aa[u] * bf2f(rr2[qq] >> 16);
            }
        }
    }
    for (; s < re; ++s) {
        const int sn = csr[s];
        const float a = __expf(lk60(als[(size_t)sn * 4 + hd] + advh));
        smw += a;
        const int4 r = *reinterpret_cast<const int4*>(hsrc + (size_t)sn * 512 + ch0);
        const u32 rr2[4] = {(u32)r.x, (u32)r.y, (u32)r.z, (u32)r.w};
#pragma unroll
        for (int qq = 0; qq < 4; ++qq) {
            acc[2*qq]   += a * bf2f(rr2[qq] & 0xffffu);
            acc[2*qq+1] += a * bf2f(rr2[qq] >> 16);
        }
    }
    const float inv = 1.f / (smw + 1e-16f);

    u16 ob[8];
#pragma unroll
    for (int j = 0; j < 8; ++j) {
        const int ch = ch0 + j;
        const float scale = gam[ch] * rsqrtf(rvar[ch] + 1e-5f);
        float val = (acc[j] * inv + bias[ch] - rmean[ch]) * scale + bet[ch];
        if (RELU) val = fmaxf(val, 0.f);
        ob[j] = f2bf(val);
    }
    int4 w;
    w.x = (int)((u32)ob[0] | ((u32)ob[1] << 16));
    w.y = (int)((u32)ob[2] | ((u32)ob[3] << 16));
    w.z = (int)((u32)ob[4] | ((u32)ob[5] << 16));
    w.w = (int)((u32)ob[6] | ((u32)ob[7] << 16));
    *reinterpret_cast<int4*>(outp + (size_t)dst * 512 + ch0) = w;
}

// ---------------------------------------------------------------- aggregate CH=128 (+BN)
// 16-lane group per dst; lane = 8ch (16B). ONE sweep, per-lane denom.
__global__ __launch_bounds__(256) void agg128_k(
    const u16* __restrict__ hsrc, const int* __restrict__ offs,
    const int* __restrict__ csr, const float* __restrict__ als,
    const float* __restrict__ ald, const float* __restrict__ bias,
    const float* __restrict__ gam, const float* __restrict__ bet,
    const float* __restrict__ rmean, const float* __restrict__ rvar,
    u16* __restrict__ outp, int N)
{
    const int tid = threadIdx.x;
    const int w = tid >> 6, g = (tid >> 4) & 3, l = tid & 15;
    const int dst = blockIdx.x * 16 + w * 4 + g;
    if (dst >= N) return;
    const int ch0 = l * 8;

    const float advh = ald[dst];
    const int rs = offs[dst], re = offs[dst + 1];

    float acc[8] = {};
    float smw = 0.f;
    int s = rs;
    for (; s + 4 <= re; s += 4) {
        int sn[4];
#pragma unroll
        for (int u = 0; u < 4; ++u) sn[u] = csr[s + u];
        int4 r[4];
#pragma unroll
        for (int u = 0; u < 4; ++u)
            r[u] = *reinterpret_cast<const int4*>(hsrc + (size_t)sn[u] * 128 + ch0);
        float aa[4];
#pragma unroll
        for (int u = 0; u < 4; ++u)
            aa[u] = __expf(lk60(als[sn[u]] + advh));
#pragma unroll
        for (int u = 0; u < 4; ++u) {
            smw += aa[u];
            const u32 rr2[4] = {(u32)r[u].x, (u32)r[u].y, (u32)r[u].z, (u32)r[u].w};
#pragma unroll
            for (int qq = 0; qq < 4; ++qq) {
                acc[2*qq]   += aa[u] * bf2f(rr2[qq] & 0xffffu);
                acc[2*qq+1] += aa[u] * bf2f(rr2[qq] >> 16);
            }
        }
    }
    for (; s < re; ++s) {
        const int sn = csr[s];
        const float a = __expf(lk60(als[sn] + advh));
        smw += a;
        const int4 r = *reinterpret_cast<const int4*>(hsrc + (size_t)sn * 128 + ch0);
        const u32 rr2[4] = {(u32)r.x, (u32)r.y, (u32)r.z, (u32)r.w};
#pragma unroll
        for (int qq = 0; qq < 4; ++qq) {
            acc[2*qq]   += a * bf2f(rr2[qq] & 0xffffu);
            acc[2*qq+1] += a * bf2f(rr2[qq] >> 16);
        }
    }
    const float inv = 1.f / (smw + 1e-16f);

    u16 ob[8];
#pragma unroll
    for (int j = 0; j < 8; ++j) {
        const int ch = ch0 + j;
        const float scale = gam[ch] * rsqrtf(rvar[ch] + 1e-5f);
        float val = (acc[j] * inv + bias[ch] - rmean[ch]) * scale + bet[ch];
        ob[j] = f2bf(val);
    }
    int4 wv;
    wv.x = (int)((u32)ob[0] | ((u32)ob[1] << 16));
    wv.y = (int)((u32)ob[2] | ((u32)ob[3] << 16));
    wv.z = (int)((u32)ob[4] | ((u32)ob[5] << 16));
    wv.w = (int)((u32)ob[6] | ((u32)ob[7] << 16));
    *reinterpret_cast<int4*>(outp + (size_t)dst * 128 + ch0) = wv;
}

// ---------------------------------------------------------------- pool
__global__ __launch_bounds__(128) void pool_k(
    const u16* __restrict__ h3, const int* __restrict__ batch,
    float* __restrict__ out, int N)
{
    const int g = blockIdx.x;
    const int t = threadIdx.x;
    int lo = 0, hi = N;
    while (lo < hi) { int mid = (lo + hi) >> 1; if (batch[mid] < g) lo = mid + 1; else hi = mid; }
    const int s0 = lo;
    lo = 0; hi = N;
    while (lo < hi) { int mid = (lo + hi) >> 1; if (batch[mid] < g + 1) lo = mid + 1; else hi = mid; }
    const int s1 = lo;
    float sum = 0.f, mx = -1e30f;
    for (int n = s0; n < s1; ++n) {
        const float v = bf2f((u32)h3[(size_t)n * 128 + t]);
        sum += v;
        mx = fmaxf(mx, v);
    }
    const int cnt = s1 - s0;
    out[(size_t)g * 256 + t]       = cnt ? sum / (float)cnt : 0.f;
    out[(size_t)g * 256 + 128 + t] = cnt ? mx : 0.f;
}

// ---------------------------------------------------------------- launch
extern "C" void kernel_launch(void* const* d_in, const int* in_sizes, int n_in,
                              void* d_out, int out_size, void* d_ws, size_t ws_size,
                              hipStream_t stream)
{
    const float* x   = (const float*)d_in[0];
    const int* ei    = (const int*)d_in[1];
    const int* batch = (const int*)d_in[2];
    const float* W1  = (const float*)d_in[3];
    const float* as1 = (const float*)d_in[4];
    const float* ad1 = (const float*)d_in[5];
    const float* b1  = (const float*)d_in[6];
    const float* g1  = (const float*)d_in[7];
    const float* bt1 = (const float*)d_in[8];
    const float* rm1 = (const float*)d_in[9];
    const float* rv1 = (const float*)d_in[10];
    const float* W2  = (const float*)d_in[11];
    const float* as2 = (const float*)d_in[12];
    const float* ad2 = (const float*)d_in[13];
    const float* b2  = (const float*)d_in[14];
    const float* g2  = (const float*)d_in[15];
    const float* bt2 = (const float*)d_in[16];
    const float* rm2 = (const float*)d_in[17];
    const float* rv2 = (const float*)d_in[18];
    const float* W3  = (const float*)d_in[19];
    const float* as3 = (const float*)d_in[20];
    const float* ad3 = (const float*)d_in[21];
    const float* b3  = (const float*)d_in[22];
    const float* g3  = (const float*)d_in[23];
    const float* bt3 = (const float*)d_in[24];
    const float* rm3 = (const float*)d_in[25];
    const float* rv3 = (const float*)d_in[26];

    const int Nn = in_sizes[2];           // 50000
    const int Ee = in_sizes[1] / 2;       // 400000
    const int ET = Ee + Nn;               // + self-loops
    const int Gg = out_size / 256;        // 512
    const int Mp = 392 * 128;             // 50176: 392 row-panels = 8 XCDs x 49

    char* ws = (char*)d_ws;
    size_t o = 0;
    auto alc = [&](size_t bytes) { size_t r = o; o = (o + bytes + 255) & ~(size_t)255; return r; };
    u16*  hA   = (u16*)(ws + alc((size_t)Mp * 512 * 2));
    u16*  hB   = (u16*)(ws + alc((size_t)Mp * 512 * 2));
    u16*  xb   = (u16*)(ws + alc((size_t)Mp * 96 * 2));
    u16*  Wt1  = (u16*)(ws + alc((size_t)512 * 96 * 2));
    u16*  Wt2  = (u16*)(ws + alc((size_t)512 * 512 * 2));
    u16*  Wt3  = (u16*)(ws + alc((size_t)128 * 512 * 2));
    float* als = (float*)(ws + alc((size_t)Nn * 4 * 4));
    float* ald = (float*)(ws + alc((size_t)Nn * 4 * 4));
    int*  cnt  = (int*)(ws + alc((size_t)2 * Nn * 4));
    int*  fill = cnt + Nn;
    int*  offs = (int*)(ws + alc((size_t)(Nn + 1) * 4));
    int*  part = (int*)(ws + alc((size_t)Nn * 4));
    int*  bsum = (int*)(ws + alc((size_t)SCAN_B * 4));
    int*  csr  = (int*)(ws + alc((size_t)ET * 4));
    (void)ws_size; (void)n_in;

    const int ETB = (ET + 255) / 256;

    // ---- prep: zero counters, then fused {count + bf16 conversions}
    hipMemsetAsync(cnt, 0, (size_t)2 * Nn * 4, stream);
    {
        const int cvt_tot = Mp * 96 + 512 * 96 + 512 * 512 + 128 * 512;
        const int cvtB = (cvt_tot + 255) / 256;
        prep_k<<<ETB + cvtB, 256, 0, stream>>>(ei + Ee, cnt, Ee,
                                               x, W1, W2, W3,
                                               xb, Wt1, Wt2, Wt3, Nn, Mp, ETB);
    }
    // ---- scan + scatter
    const int nb = (Nn + SCAN_B - 1) / SCAN_B;
    scan1_k<<<nb, SCAN_B, 0, stream>>>(cnt, part, bsum, Nn);
    scan2_k<<<1, SCAN_B, 0, stream>>>(bsum, nb);
    scan3_k<<<nb, SCAN_B, 0, stream>>>(part, bsum, offs, Nn);
    scatter_k<<<ETB, 256, 0, stream>>>(ei, ei + Ee, offs, fill, csr, Ee, Nn);

    const int nwb4  = (Nn + 3) / 4;    // agg512: 4 dst/block
    const int nwb16 = (Nn + 15) / 16;  // agg128: 16 dst/block
    const int nwg4 = 392 * 4;
    const int nwg1 = 392;

    // ---- layer 1
    mgemm_k<<<nwg4, 256, 0, stream>>>(xb, Wt1, hA, as1, ad1, als, ald, Nn, 96, 512, 4, 4);
    agg512_k<true><<<nwb4, 256, 0, stream>>>(hA, offs, csr, als, ald,
                                             b1, g1, bt1, rm1, rv1, hB, Nn);
    // ---- layer 2
    mgemm_k<<<nwg4, 256, 0, stream>>>(hB, Wt2, hA, as2, ad2, als, ald, Nn, 512, 512, 4, 4);
    agg512_k<true><<<nwb4, 256, 0, stream>>>(hA, offs, csr, als, ald,
                                             b2, g2, bt2, rm2, rv2, hB, Nn);
    // ---- layer 3
    mgemm_k<<<nwg1, 256, 0, stream>>>(hB, Wt3, hA, as3, ad3, als, ald, Nn, 512, 128, 1, 1);
    agg128_k<<<nwb16, 256, 0, stream>>>(hA, offs, csr, als, ald,
                                        b3, g3, bt3, rm3, rv3, hB, Nn);
    // ---- global mean+max pool
    pool_k<<<Gg, 128, 0, stream>>>(hB, batch, (float*)d_out, Nn);
}

// Round 14
// 363.213 us; speedup vs baseline: 1.0149x; 1.0149x over previous
//
#include <hip/hip_runtime.h>

typedef unsigned short u16;
typedef unsigned int u32;
typedef __attribute__((ext_vector_type(8))) short s16x8;
typedef __attribute__((ext_vector_type(4))) float f32x4;

__device__ __forceinline__ float bf2f(u32 u) {
    return __uint_as_float(u << 16);
}
__device__ __forceinline__ u16 f2bf(float f) {
    u32 x = __float_as_uint(f);
    u32 r = (x + 0x7fffu + ((x >> 16) & 1u)) >> 16;   // round-nearest-even
    return (u16)r;
}

__device__ __forceinline__ void gload16(const u16* g, u16* l) {
    __builtin_amdgcn_global_load_lds(
        (const __attribute__((address_space(1))) unsigned int*)g,
        (__attribute__((address_space(3))) unsigned int*)l,
        16, 0, 0);
}

// leaky-relu then clamp: overflow-safe shiftless softmax (exact; logits O(10))
__device__ __forceinline__ float lk60(float e) {
    e = (e > 0.f) ? e : 0.2f * e;
    return fminf(e, 60.f);
}

// ---------------------------------------------------------------- fused prep + edge count
__global__ __launch_bounds__(256) void prep_k(
    const int* __restrict__ edst,  int* __restrict__ cnt, int E_,
    const float* __restrict__ x, const float* __restrict__ W1,
    const float* __restrict__ W2, const float* __restrict__ W3,
    u16* __restrict__ xb, u16* __restrict__ Wt1,
    u16* __restrict__ Wt2, u16* __restrict__ Wt3, int N, int Mp, int ETB)
{
    if ((int)blockIdx.x < ETB) {
        const int i = blockIdx.x * 256 + threadIdx.x;
        if (i >= E_ + N) return;
        const int d = (i < E_) ? edst[i] : (i - E_);
        atomicAdd(&cnt[d], 1);
        return;
    }
    const int i = ((int)blockIdx.x - ETB) * 256 + threadIdx.x;
    const int n1 = Mp * 96;
    const int n2 = 512 * 96;
    const int n3 = 512 * 512;
    const int n4 = 128 * 512;
    if (i < n1) {
        const int r = i / 96, c = i - r * 96;
        xb[i] = f2bf((r < N && c < 75) ? x[(size_t)r * 75 + c] : 0.f);
    } else if (i < n1 + n2) {
        const int j = i - n1;
        const int n = j / 96, k = j - n * 96;
        Wt1[j] = f2bf(k < 75 ? W1[(size_t)k * 512 + n] : 0.f);
    } else if (i < n1 + n2 + n3) {
        const int j = i - n1 - n2;
        const int n = j >> 9, k = j & 511;
        Wt2[j] = f2bf(W2[(size_t)k * 512 + n]);
    } else if (i < n1 + n2 + n3 + n4) {
        const int j = i - n1 - n2 - n3;
        const int n = j >> 9, k = j & 511;
        Wt3[j] = f2bf(W3[(size_t)k * 128 + n]);
    }
}

// ---------------------------------------------------------------- 3-kernel scan
#define SCAN_B 256
__global__ void scan1_k(const int* __restrict__ cnt, int* __restrict__ part,
                        int* __restrict__ bsum, int n)
{
    __shared__ int sm[SCAN_B];
    const int idx = blockIdx.x * SCAN_B + threadIdx.x;
    int v = (idx < n) ? cnt[idx] : 0;
    sm[threadIdx.x] = v;
    __syncthreads();
    for (int off = 1; off < SCAN_B; off <<= 1) {
        int t2 = (threadIdx.x >= off) ? sm[threadIdx.x - off] : 0;
        __syncthreads();
        sm[threadIdx.x] += t2;
        __syncthreads();
    }
    if (idx < n) part[idx] = sm[threadIdx.x];
    if (threadIdx.x == SCAN_B - 1) bsum[blockIdx.x] = sm[threadIdx.x];
}

__global__ void scan2_k(int* __restrict__ bsum, int nb)
{
    __shared__ int sm[SCAN_B];
    const int t = threadIdx.x;
    int v = (t < nb) ? bsum[t] : 0;
    sm[t] = v;
    __syncthreads();
    for (int off = 1; off < SCAN_B; off <<= 1) {
        int t2 = (t >= off) ? sm[t - off] : 0;
        __syncthreads();
        sm[t] += t2;
        __syncthreads();
    }
    if (t < nb) bsum[t] = sm[t] - v;   // exclusive
}

__global__ void scan3_k(const int* __restrict__ part, const int* __restrict__ boff,
                        int* __restrict__ offs, int n)
{
    const int idx = blockIdx.x * SCAN_B + threadIdx.x;
    if (idx < n) offs[idx + 1] = part[idx] + boff[idx / SCAN_B];
    if (idx == 0) offs[0] = 0;
}

// ---------------------------------------------------------------- MFMA GEMM 128x256 + fused logits (N=512 layers)
// C[M,512] = A[M,K] @ Bt[512,K]^T. 512 threads = 8 waves (2 row x 4 col),
// each wave 64x64 (4x4 frags). Double-buffered LDS, 2-phase prefetch.
// Block covers 256 cols = 2 heads; epilogue computes als/ald for both.
__global__ __launch_bounds__(512) void mg256_k(
    const u16* __restrict__ A, const u16* __restrict__ Bt, u16* __restrict__ C,
    const float* __restrict__ avs, const float* __restrict__ avd,
    float* __restrict__ als, float* __restrict__ ald,
    int M, int K)
{
    __shared__ u16 Al[2][128 * 32];   // 8 KB each
    __shared__ u16 Bl[2][256 * 32];   // 16 KB each
    const int t = threadIdx.x;
    const int lane = t & 63;
    const int wid = t >> 6;           // 0..7
    const int wr = wid >> 2;          // 0..1 (row half)
    const int wc = wid & 3;           // 0..3 (col quarter)
    const int rr = lane & 15, q = lane >> 4;

    // XCD swizzle: grid = 784 = 8 x 98; 2 col-blocks per row-panel.
    const int dd = blockIdx.x;
    const int xcd = dd & 7, ii = dd >> 3;            // ii in 0..97
    const int yb = xcd * 49 + (ii >> 1);
    const int cb = ii & 1;
    const int m0 = yb * 128, n0 = cb * 256;
    const int h0 = cb * 2;                           // first head of this block

    f32x4 acc[4][4];
#pragma unroll
    for (int m = 0; m < 4; ++m)
#pragma unroll
        for (int n = 0; n < 4; ++n) acc[m][n] = (f32x4){0.f, 0.f, 0.f, 0.f};

    auto stage = [&](int b, int k0) {
        {   // A: 128 rows, 1 iteration of 512 threads
            const int r = t >> 2, s = t & 3;
            const int g = s ^ ((r >> 1) & 3);
            gload16(A + (size_t)(m0 + r) * K + k0 + g * 8, &Al[b][t * 8]);
        }
#pragma unroll
        for (int i2 = 0; i2 < 2; ++i2) {   // B: 256 rows, 2 iterations
            const int si = i2 * 512 + t;
            const int r = si >> 2, s = si & 3;
            const int g = s ^ ((r >> 1) & 3);
            gload16(Bt + (size_t)(n0 + r) * K + k0 + g * 8, &Bl[b][si * 8]);
        }
    };

    const int nk = K >> 5;
    stage(0, 0);
    __syncthreads();
    int buf = 0;
    for (int kt = 0; kt < nk; ++kt) {
        if (kt + 1 < nk) stage(buf ^ 1, (kt + 1) << 5);
        s16x8 af[4], bfr[4];
#pragma unroll
        for (int m = 0; m < 4; ++m) {
            const int r = wr * 64 + m * 16 + rr;
            af[m] = *reinterpret_cast<const s16x8*>(&Al[buf][r * 32 + ((q ^ ((r >> 1) & 3)) << 3)]);
        }
#pragma unroll
        for (int n = 0; n < 4; ++n) {
            const int r = wc * 64 + n * 16 + rr;
            bfr[n] = *reinterpret_cast<const s16x8*>(&Bl[buf][r * 32 + ((q ^ ((r >> 1) & 3)) << 3)]);
        }
#pragma unroll
        for (int m = 0; m < 4; ++m)
#pragma unroll
            for (int n = 0; n < 4; ++n)
                acc[m][n] = __builtin_amdgcn_mfma_f32_16x16x32_bf16(af[m], bfr[n], acc[m][n], 0, 0, 0);
        __syncthreads();
        buf ^= 1;
    }

    // h write: row = (lane>>4)*4+j, col = lane&15 within each fragment
#pragma unroll
    for (int m = 0; m < 4; ++m) {
        const int row_b = m0 + wr * 64 + m * 16 + q * 4;
#pragma unroll
        for (int j = 0; j < 4; ++j) {
            const int row = row_b + j;
            if (row < M) {
#pragma unroll
                for (int n = 0; n < 4; ++n) {
                    const int col = n0 + wc * 64 + n * 16 + rr;
                    C[(size_t)row * 512 + col] = f2bf(acc[m][n][j]);
                }
            }
        }
    }

    // fused logits: wave wc covers head h0 + (wc>>1), col half (wc&1)*64
    const int hw = h0 + (wc >> 1);
    float asv[4], adv[4];
#pragma unroll
    for (int n = 0; n < 4; ++n) {
        const int c = (wc & 1) * 64 + n * 16 + rr;   // channel within head
        asv[n] = avs[hw * 128 + c];
        adv[n] = avd[hw * 128 + c];
    }
    float* lps = (float*)&Al[0][0];        // [4 wc][128 rows]
    float* lpd = lps + 512;
#pragma unroll
    for (int m = 0; m < 4; ++m)
#pragma unroll
        for (int j = 0; j < 4; ++j) {
            float ps = 0.f, pd = 0.f;
#pragma unroll
            for (int n = 0; n < 4; ++n) {
                ps += acc[m][n][j] * asv[n];
                pd += acc[m][n][j] * adv[n];
            }
#pragma unroll
            for (int off = 1; off < 16; off <<= 1) {
                ps += __shfl_xor(ps, off, 64);
                pd += __shfl_xor(pd, off, 64);
            }
            if (rr == 0) {
                const int r = wr * 64 + m * 16 + q * 4 + j;
                lps[wc * 128 + r] = ps;
                lpd[wc * 128 + r] = pd;
            }
        }
    __syncthreads();
    if (t < 256) {
        const int r = t & 127, pair = t >> 7;        // pair = head offset 0/1
        const int row = m0 + r;
        if (row < M) {
            als[(size_t)row * 4 + h0 + pair] = lps[(2 * pair) * 128 + r] + lps[(2 * pair + 1) * 128 + r];
            ald[(size_t)row * 4 + h0 + pair] = lpd[(2 * pair) * 128 + r] + lpd[(2 * pair + 1) * 128 + r];
        }
    }
}

// ---------------------------------------------------------------- MFMA GEMM 128x128 + fused logits (layer 3, N=128)
__global__ __launch_bounds__(256) void mgemm_k(
    const u16* __restrict__ A, const u16* __restrict__ Bt, u16* __restrict__ C,
    const float* __restrict__ avs, const float* __restrict__ avd,
    float* __restrict__ als, float* __restrict__ ald,
    int M, int K, int Ncol, int H, int NXB)
{
    __shared__ u16 Al[2][128 * 32];
    __shared__ u16 Bl[2][128 * 32];
    const int t = threadIdx.x;
    const int lane = t & 63;
    const int wid = t >> 6;
    const int wr = wid >> 1, wc = wid & 1;
    const int rr = lane & 15, q = lane >> 4;

    const int dd = blockIdx.x;
    const int xcd = dd & 7, ii = dd >> 3;
    const int gpx = (int)(gridDim.x >> 3) / NXB;
    const int yb = xcd * gpx + ((NXB == 4) ? (ii >> 2) : ii);
    const int head = (NXB == 4) ? (ii & 3) : 0;
    const int m0 = yb * 128, n0 = head * 128;

    f32x4 acc[4][4];
#pragma unroll
    for (int m = 0; m < 4; ++m)
#pragma unroll
        for (int n = 0; n < 4; ++n) acc[m][n] = (f32x4){0.f, 0.f, 0.f, 0.f};

    auto stage = [&](int b, int k0) {
#pragma unroll
        for (int i2 = 0; i2 < 2; ++i2) {
            const int si = i2 * 256 + t;
            const int r = si >> 2, s = si & 3;
            const int g = s ^ ((r >> 1) & 3);
            gload16(A  + (size_t)(m0 + r) * K + k0 + g * 8, &Al[b][si * 8]);
            gload16(Bt + (size_t)(n0 + r) * K + k0 + g * 8, &Bl[b][si * 8]);
        }
    };

    const int nk = K >> 5;
    stage(0, 0);
    __syncthreads();
    int buf = 0;
    for (int kt = 0; kt < nk; ++kt) {
        if (kt + 1 < nk) stage(buf ^ 1, (kt + 1) << 5);
        s16x8 af[4], bfr[4];
#pragma unroll
        for (int m = 0; m < 4; ++m) {
            const int r = wr * 64 + m * 16 + rr;
            af[m] = *reinterpret_cast<const s16x8*>(&Al[buf][r * 32 + ((q ^ ((r >> 1) & 3)) << 3)]);
        }
#pragma unroll
        for (int n = 0; n < 4; ++n) {
            const int r = wc * 64 + n * 16 + rr;
            bfr[n] = *reinterpret_cast<const s16x8*>(&Bl[buf][r * 32 + ((q ^ ((r >> 1) & 3)) << 3)]);
        }
#pragma unroll
        for (int m = 0; m < 4; ++m)
#pragma unroll
            for (int n = 0; n < 4; ++n)
                acc[m][n] = __builtin_amdgcn_mfma_f32_16x16x32_bf16(af[m], bfr[n], acc[m][n], 0, 0, 0);
        __syncthreads();
        buf ^= 1;
    }

#pragma unroll
    for (int m = 0; m < 4; ++m) {
        const int row_b = m0 + wr * 64 + m * 16 + q * 4;
#pragma unroll
        for (int j = 0; j < 4; ++j) {
            const int row = row_b + j;
            if (row < M) {
#pragma unroll
                for (int n = 0; n < 4; ++n) {
                    const int col = n0 + wc * 64 + n * 16 + rr;
                    C[(size_t)row * Ncol + col] = f2bf(acc[m][n][j]);
                }
            }
        }
    }

    // fused logits
    float asv[4], adv[4];
#pragma unroll
    for (int n = 0; n < 4; ++n) {
        const int c = wc * 64 + n * 16 + rr;
        asv[n] = avs[head * 128 + c];
        adv[n] = avd[head * 128 + c];
    }
    float* lps = (float*)&Al[0][0];
    float* lpd = lps + 256;
#pragma unroll
    for (int m = 0; m < 4; ++m)
#pragma unroll
        for (int j = 0; j < 4; ++j) {
            float ps = 0.f, pd = 0.f;
#pragma unroll
            for (int n = 0; n < 4; ++n) {
                ps += acc[m][n][j] * asv[n];
                pd += acc[m][n][j] * adv[n];
            }
#pragma unroll
            for (int off = 1; off < 16; off <<= 1) {
                ps += __shfl_xor(ps, off, 64);
                pd += __shfl_xor(pd, off, 64);
            }
            if (rr == 0) {
                const int r = wr * 64 + m * 16 + q * 4 + j;
                lps[wc * 128 + r] = ps;
                lpd[wc * 128 + r] = pd;
            }
        }
    __syncthreads();
    if (t < 128) {
        const int row = m0 + t;
        if (row < M) {
            als[(size_t)row * H + head] = lps[t] + lps[128 + t];
            ald[(size_t)row * H + head] = lpd[t] + lpd[128 + t];
        }
    }
}

// ---------------------------------------------------------------- scatter
__global__ void scatter_k(const int* __restrict__ esrc, const int* __restrict__ edst,
                          const int* __restrict__ offs, int* __restrict__ fill,
                          int* __restrict__ csr, int E_, int N_)
{
    const int i = blockIdx.x * 256 + threadIdx.x;
    if (i >= E_ + N_) return;
    int s, d;
    if (i < E_) { s = esrc[i]; d = edst[i]; } else { s = d = i - E_; }
    const int pos = offs[d] + atomicAdd(&fill[d], 1);
    csr[pos] = s;
}

// ---------------------------------------------------------------- aggregate CH=512 (+BN+ReLU)
// one wave per dst; ONE-sweep unnormalized softmax; 4 edges in flight, 16B/lane.
template<bool RELU>
__global__ __launch_bounds__(256) void agg512_k(
    const u16* __restrict__ hsrc, const int* __restrict__ offs,
    const int* __restrict__ csr, const float* __restrict__ als,
    const float* __restrict__ ald, const float* __restrict__ bias,
    const float* __restrict__ gam, const float* __restrict__ bet,
    const float* __restrict__ rmean, const float* __restrict__ rvar,
    u16* __restrict__ outp, int N)
{
    const int lane = threadIdx.x & 63;
    const int dst = blockIdx.x * 4 + (threadIdx.x >> 6);
    if (dst >= N) return;
    const int ch0 = lane * 8;
    const int hd = lane >> 4;

    const float advh = ald[(size_t)dst * 4 + hd];
    const int rs = offs[dst], re = offs[dst + 1];

    float acc[8] = {};
    float smw = 0.f;
    int s = rs;
    for (; s + 4 <= re; s += 4) {
        int sn[4];
#pragma unroll
        for (int u = 0; u < 4; ++u) sn[u] = csr[s + u];
        int4 r[4];
#pragma unroll
        for (int u = 0; u < 4; ++u)
            r[u] = *reinterpret_cast<const int4*>(hsrc + (size_t)sn[u] * 512 + ch0);
        float aa[4];
#pragma unroll
        for (int u = 0; u < 4; ++u)
            aa[u] = __expf(lk60(als[(size_t)sn[u] * 4 + hd] + advh));
#pragma unroll
        for (int u = 0; u < 4; ++u) {
            smw += aa[u];
            const u32 rr2[4] = {(u32)r[u].x, (u32)r[u].y, (u32)r[u].z, (u32)r[u].w};
#pragma unroll
            for (int qq = 0; qq < 4; ++qq) {
                acc[2*qq]   += aa[u] * bf2f(rr2[qq] & 0xffffu);
                acc[2*qq+1] += aa[u] * bf2f(rr2[qq] >> 16);
            }
        }
    }
    for (; s < re; ++s) {
        const int sn = csr[s];
        const float a = __expf(lk60(als[(size_t)sn * 4 + hd] + advh));
        smw += a;
        const int4 r = *reinterpret_cast<const int4*>(hsrc + (size_t)sn * 512 + ch0);
        const u32 rr2[4] = {(u32)r.x, (u32)r.y, (u32)r.z, (u32)r.w};
#pragma unroll
        for (int qq = 0; qq < 4; ++qq) {
            acc[2*qq]   += a * bf2f(rr2[qq] & 0xffffu);
            acc[2*qq+1] += a * bf2f(rr2[qq] >> 16);
        }
    }
    const float inv = 1.f / (smw + 1e-16f);

    u16 ob[8];
#pragma unroll
    for (int j = 0; j < 8; ++j) {
        const int ch = ch0 + j;
        const float scale = gam[ch] * rsqrtf(rvar[ch] + 1e-5f);
        float val = (acc[j] * inv + bias[ch] - rmean[ch]) * scale + bet[ch];
        if (RELU) val = fmaxf(val, 0.f);
        ob[j] = f2bf(val);
    }
    int4 w;
    w.x = (int)((u32)ob[0] | ((u32)ob[1] << 16));
    w.y = (int)((u32)ob[2] | ((u32)ob[3] << 16));
    w.z = (int)((u32)ob[4] | ((u32)ob[5] << 16));
    w.w = (int)((u32)ob[6] | ((u32)ob[7] << 16));
    *reinterpret_cast<int4*>(outp + (size_t)dst * 512 + ch0) = w;
}

// ---------------------------------------------------------------- aggregate CH=128 (+BN)
__global__ __launch_bounds__(256) void agg128_k(
    const u16* __restrict__ hsrc, const int* __restrict__ offs,
    const int* __restrict__ csr, const float* __restrict__ als,
    const float* __restrict__ ald, const float* __restrict__ bias,
    const float* __restrict__ gam, const float* __restrict__ bet,
    const float* __restrict__ rmean, const float* __restrict__ rvar,
    u16* __restrict__ outp, int N)
{
    const int tid = threadIdx.x;
    const int w = tid >> 6, g = (tid >> 4) & 3, l = tid & 15;
    const int dst = blockIdx.x * 16 + w * 4 + g;
    if (dst >= N) return;
    const int ch0 = l * 8;

    const float advh = ald[dst];
    const int rs = offs[dst], re = offs[dst + 1];

    float acc[8] = {};
    float smw = 0.f;
    int s = rs;
    for (; s + 4 <= re; s += 4) {
        int sn[4];
#pragma unroll
        for (int u = 0; u < 4; ++u) sn[u] = csr[s + u];
        int4 r[4];
#pragma unroll
        for (int u = 0; u < 4; ++u)
            r[u] = *reinterpret_cast<const int4*>(hsrc + (size_t)sn[u] * 128 + ch0);
        float aa[4];
#pragma unroll
        for (int u = 0; u < 4; ++u)
            aa[u] = __expf(lk60(als[sn[u]] + advh));
#pragma unroll
        for (int u = 0; u < 4; ++u) {
            smw += aa[u];
            const u32 rr2[4] = {(u32)r[u].x, (u32)r[u].y, (u32)r[u].z, (u32)r[u].w};
#pragma unroll
            for (int qq = 0; qq < 4; ++qq) {
                acc[2*qq]   += aa[u] * bf2f(rr2[qq] & 0xffffu);
                acc[2*qq+1] += aa[u] * bf2f(rr2[qq] >> 16);
            }
        }
    }
    for (; s < re; ++s) {
        const int sn = csr[s];
        const float a = __expf(lk60(als[sn] + advh));
        smw += a;
        const int4 r = *reinterpret_cast<const int4*>(hsrc + (size_t)sn * 128 + ch0);
        const u32 rr2[4] = {(u32)r.x, (u32)r.y, (u32)r.z, (u32)r.w};
#pragma unroll
        for (int qq = 0; qq < 4; ++qq) {
            acc[2*qq]   += a * bf2f(rr2[qq] & 0xffffu);
            acc[2*qq+1] += a * bf2f(rr2[qq] >> 16);
        }
    }
    const float inv = 1.f / (smw + 1e-16f);

    u16 ob[8];
#pragma unroll
    for (int j = 0; j < 8; ++j) {
        const int ch = ch0 + j;
        const float scale = gam[ch] * rsqrtf(rvar[ch] + 1e-5f);
        float val = (acc[j] * inv + bias[ch] - rmean[ch]) * scale + bet[ch];
        ob[j] = f2bf(val);
    }
    int4 wv;
    wv.x = (int)((u32)ob[0] | ((u32)ob[1] << 16));
    wv.y = (int)((u32)ob[2] | ((u32)ob[3] << 16));
    wv.z = (int)((u32)ob[4] | ((u32)ob[5] << 16));
    wv.w = (int)((u32)ob[6] | ((u32)ob[7] << 16));
    *reinterpret_cast<int4*>(outp + (size_t)dst * 128 + ch0) = wv;
}

// ---------------------------------------------------------------- pool
__global__ __launch_bounds__(128) void pool_k(
    const u16* __restrict__ h3, const int* __restrict__ batch,
    float* __restrict__ out, int N)
{
    const int g = blockIdx.x;
    const int t = threadIdx.x;
    int lo = 0, hi = N;
    while (lo < hi) { int mid = (lo + hi) >> 1; if (batch[mid] < g) lo = mid + 1; else hi = mid; }
    const int s0 = lo;
    lo = 0; hi = N;
    while (lo < hi) { int mid = (lo + hi) >> 1; if (batch[mid] < g + 1) lo = mid + 1; else hi = mid; }
    const int s1 = lo;
    float sum = 0.f, mx = -1e30f;
    for (int n = s0; n < s1; ++n) {
        const float v = bf2f((u32)h3[(size_t)n * 128 + t]);
        sum += v;
        mx = fmaxf(mx, v);
    }
    const int cnt = s1 - s0;
    out[(size_t)g * 256 + t]       = cnt ? sum / (float)cnt : 0.f;
    out[(size_t)g * 256 + 128 + t] = cnt ? mx : 0.f;
}

// ---------------------------------------------------------------- launch
extern "C" void kernel_launch(void* const* d_in, const int* in_sizes, int n_in,
                              void* d_out, int out_size, void* d_ws, size_t ws_size,
                              hipStream_t stream)
{
    const float* x   = (const float*)d_in[0];
    const int* ei    = (const int*)d_in[1];
    const int* batch = (const int*)d_in[2];
    const float* W1  = (const float*)d_in[3];
    const float* as1 = (const float*)d_in[4];
    const float* ad1 = (const float*)d_in[5];
    const float* b1  = (const float*)d_in[6];
    const float* g1  = (const float*)d_in[7];
    const float* bt1 = (const float*)d_in[8];
    const float* rm1 = (const float*)d_in[9];
    const float* rv1 = (const float*)d_in[10];
    const float* W2  = (const float*)d_in[11];
    const float* as2 = (const float*)d_in[12];
    const float* ad2 = (const float*)d_in[13];
    const float* b2  = (const float*)d_in[14];
    const float* g2  = (const float*)d_in[15];
    const float* bt2 = (const float*)d_in[16];
    const float* rm2 = (const float*)d_in[17];
    const float* rv2 = (const float*)d_in[18];
    const float* W3  = (const float*)d_in[19];
    const float* as3 = (const float*)d_in[20];
    const float* ad3 = (const float*)d_in[21];
    const float* b3  = (const float*)d_in[22];
    const float* g3  = (const float*)d_in[23];
    const float* bt3 = (const float*)d_in[24];
    const float* rm3 = (const float*)d_in[25];
    const float* rv3 = (const float*)d_in[26];

    const int Nn = in_sizes[2];           // 50000
    const int Ee = in_sizes[1] / 2;       // 400000
    const int ET = Ee + Nn;               // + self-loops
    const int Gg = out_size / 256;        // 512
    const int Mp = 392 * 128;             // 50176: 392 row-panels = 8 XCDs x 49

    char* ws = (char*)d_ws;
    size_t o = 0;
    auto alc = [&](size_t bytes) { size_t r = o; o = (o + bytes + 255) & ~(size_t)255; return r; };
    u16*  hA   = (u16*)(ws + alc((size_t)Mp * 512 * 2));
    u16*  hB   = (u16*)(ws + alc((size_t)Mp * 512 * 2));
    u16*  xb   = (u16*)(ws + alc((size_t)Mp * 96 * 2));
    u16*  Wt1  = (u16*)(ws + alc((size_t)512 * 96 * 2));
    u16*  Wt2  = (u16*)(ws + alc((size_t)512 * 512 * 2));
    u16*  Wt3  = (u16*)(ws + alc((size_t)128 * 512 * 2));
    float* als = (float*)(ws + alc((size_t)Nn * 4 * 4));
    float* ald = (float*)(ws + alc((size_t)Nn * 4 * 4));
    int*  cnt  = (int*)(ws + alc((size_t)2 * Nn * 4));
    int*  fill = cnt + Nn;
    int*  offs = (int*)(ws + alc((size_t)(Nn + 1) * 4));
    int*  part = (int*)(ws + alc((size_t)Nn * 4));
    int*  bsum = (int*)(ws + alc((size_t)SCAN_B * 4));
    int*  csr  = (int*)(ws + alc((size_t)ET * 4));
    (void)ws_size; (void)n_in;

    const int ETB = (ET + 255) / 256;

    // ---- prep: zero counters, then fused {count + bf16 conversions}
    hipMemsetAsync(cnt, 0, (size_t)2 * Nn * 4, stream);
    {
        const int cvt_tot = Mp * 96 + 512 * 96 + 512 * 512 + 128 * 512;
        const int cvtB = (cvt_tot + 255) / 256;
        prep_k<<<ETB + cvtB, 256, 0, stream>>>(ei + Ee, cnt, Ee,
                                               x, W1, W2, W3,
                                               xb, Wt1, Wt2, Wt3, Nn, Mp, ETB);
    }
    // ---- scan + scatter
    const int nb = (Nn + SCAN_B - 1) / SCAN_B;
    scan1_k<<<nb, SCAN_B, 0, stream>>>(cnt, part, bsum, Nn);
    scan2_k<<<1, SCAN_B, 0, stream>>>(bsum, nb);
    scan3_k<<<nb, SCAN_B, 0, stream>>>(part, bsum, offs, Nn);
    scatter_k<<<ETB, 256, 0, stream>>>(ei, ei + Ee, offs, fill, csr, Ee, Nn);

    const int nwb4  = (Nn + 3) / 4;    // agg512: 4 dst/block
    const int nwb16 = (Nn + 15) / 16;  // agg128: 16 dst/block
    const int nwg256 = 392 * 2;        // mg256: 2 col-blocks per row-panel
    const int nwg1 = 392;              // layer-3 GEMM

    // ---- layer 1
    mg256_k<<<nwg256, 512, 0, stream>>>(xb, Wt1, hA, as1, ad1, als, ald, Nn, 96);
    agg512_k<true><<<nwb4, 256, 0, stream>>>(hA, offs, csr, als, ald,
                                             b1, g1, bt1, rm1, rv1, hB, Nn);
    // ---- layer 2
    mg256_k<<<nwg256, 512, 0, stream>>>(hB, Wt2, hA, as2, ad2, als, ald, Nn, 512);
    agg512_k<true><<<nwb4, 256, 0, stream>>>(hA, offs, csr, als, ald,
                                             b2, g2, bt2, rm2, rv2, hB, Nn);
    // ---- layer 3
    mgemm_k<<<nwg1, 256, 0, stream>>>(hB, Wt3, hA, as3, ad3, als, ald, Nn, 512, 128, 1, 1);
    agg128_k<<<nwb16, 256, 0, stream>>>(hA, offs, csr, als, ald,
                                        b3, g3, bt3, rm3, rv3, hB, Nn);
    // ---- global mean+max pool
    pool_k<<<Gg, 128, 0, stream>>>(hB, batch, (float*)d_out, Nn);
}